// Round 6
// baseline (145.907 us; speedup 1.0000x reference)
//
#include <hip/hip_runtime.h>
#include <stdint.h>

typedef __bf16    bf16x8  __attribute__((ext_vector_type(8)));
typedef float     f32x16v __attribute__((ext_vector_type(16)));
typedef float     f32x4v  __attribute__((ext_vector_type(4)));
typedef float     f32x2v  __attribute__((ext_vector_type(2)));
typedef uint32_t  u32x4v  __attribute__((ext_vector_type(4)));
typedef unsigned short u16;

__device__ __forceinline__ u16 f32_to_bf16_rne(float f) {
  uint32_t u = __builtin_bit_cast(uint32_t, f);
  return (u16)((u + 0x7fffu + ((u >> 16) & 1u)) >> 16);
}

__device__ __forceinline__ uint32_t lds_addr(const void* p) {
  return (uint32_t)(uintptr_t)(__attribute__((address_space(3))) const uint8_t*)p;
}

__device__ __forceinline__ f32x16v mfma16(u32x4v a, u32x4v b, f32x16v c) {
  return __builtin_amdgcn_mfma_f32_32x32x16_bf16(
      __builtin_bit_cast(bf16x8, a), __builtin_bit_cast(bf16x8, b), c, 0, 0, 0);
}

// prep: W f32 [65][i=64][k=64] -> fragment-major bf16 arrays (B-operand form).
// elem idx = jj*4096 + (ct*4+s)*512 + l*8 + e  (l = lane)
//   w1f: W[jj][ i=s*16+(l>>5)*8+e ][ k=ct*32+(l&31) ]
//   w2f: W[jj][ e_row=ct*32+(l&31) ][ k=s*16+(l>>5)*8+e ]
__global__ __launch_bounds__(256) void prep_w(const float* __restrict__ W,
                                              u16* __restrict__ w1f,
                                              u16* __restrict__ w2f) {
  __shared__ float Wl[4096];
  const int jj = blockIdx.x;
  const int t  = threadIdx.x;
  for (int idx = t; idx < 4096; idx += 256) Wl[idx] = W[jj * 4096 + idx];
  __syncthreads();
  for (int p = t; p < 512; p += 256) {
    const int c2 = p >> 6, l = p & 63;
    const int ct = c2 >> 2, s = c2 & 3;
    const int rowA = ct * 32 + (l & 31);
    const int k0   = s * 16 + (l >> 5) * 8;
    u16 v1[8], v2[8];
    #pragma unroll
    for (int e = 0; e < 8; ++e) {
      v2[e] = f32_to_bf16_rne(Wl[rowA * 64 + k0 + e]);
      v1[e] = f32_to_bf16_rne(Wl[(k0 + e) * 64 + rowA]);
    }
    u32x4v pk1, pk2;
    #pragma unroll
    for (int q = 0; q < 4; ++q) {
      pk1[q] = (uint32_t)v1[2*q] | ((uint32_t)v1[2*q+1] << 16);
      pk2[q] = (uint32_t)v2[2*q] | ((uint32_t)v2[2*q+1] << 16);
    }
    *reinterpret_cast<u32x4v*>(w1f + jj * 4096 + p * 8) = pk1;
    *reinterpret_cast<u32x4v*>(w2f + jj * 4096 + p * 8) = pk2;
  }
}

// main: grid 256 (1 block/CU), 512 thr (8 waves = 4 jq x 2 ct), 128 samples.
// Each wave: 4 sample-tiles (4x W-register-reuse), private 3-buffer LDS ring
// staged with global_load_lds, counted vmcnt. No barriers in the K-loop.
__global__ __launch_bounds__(512, 2) void rquad_main(
    const float* __restrict__ x, const float* __restrict__ g,
    const u16* __restrict__ w1f, const u16* __restrict__ w2f,
    float* __restrict__ out) {
  __shared__ uint32_t stage[8 * 3072];   // 96 KB: [wave][3 rings][4 KB]
  __shared__ u16   x1b[128 * 66];        // bf16 x1, 16.5 KB
  __shared__ float vl [128 * 68];        // 34.8 KB combine buffer [b][k]

  const int t    = threadIdx.x;
  const int lane = t & 63;
  const int wv   = t >> 6;
  const int jq   = wv >> 1;
  const int ct   = wv & 1;
  const int bl   = lane & 31;
  const int half = lane >> 5;
  const long base = (long)blockIdx.x * 128;
  const int rot  = (int)((blockIdx.x * 23u) % 65u);
  const int j0   = jq * 16;
  const int jn   = (jq == 3) ? 17 : 16;

  for (int idx = t; idx < 128 * 64; idx += 512) {
    int s = idx >> 6, c = idx & 63;
    x1b[s * 66 + c] = f32_to_bf16_rne(x[(base + s) * 64 + c]);
  }
  if (t < 128) x1b[t * 66 + 64] = (u16)0x3F80;
  for (int idx = t; idx < 128 * 68; idx += 512) vl[idx] = 0.0f;

  // K-side slices (g for pass1, v for pass2) as f32x2 pairs: kk[tile][s][pair]
  f32x2v kk[4][4][4];
  #pragma unroll
  for (int T = 0; T < 4; ++T)
    #pragma unroll
    for (int s = 0; s < 4; ++s) {
      const float* gp = g + (base + T * 32 + bl) * 64 + s * 16 + half * 8;
      f32x4v a = *reinterpret_cast<const f32x4v*>(gp);
      f32x4v b = *reinterpret_cast<const f32x4v*>(gp + 4);
      kk[T][s][0][0] = a[0]; kk[T][s][0][1] = a[1];
      kk[T][s][1][0] = a[2]; kk[T][s][1][1] = a[3];
      kk[T][s][2][0] = b[0]; kk[T][s][2][1] = b[1];
      kk[T][s][3][0] = b[2]; kk[T][s][3][1] = b[3];
    }

  const uint32_t stg = lds_addr(&stage[0]) + wv * 12288;
  uint32_t xad[4];
  #pragma unroll
  for (int T = 0; T < 4; ++T) xad[T] = lds_addr(&x1b[0]) + (T * 32 + bl) * 132;

  f32x16v acc[4];

  __syncthreads();

  auto jidx = [&](int i) { int jj = j0 + i + rot; if (jj >= 65) jj -= 65; return jj; };

  auto issue = [&](const u16* __restrict__ Wsrc, int jj, int ring) {
    const u16* gp = Wsrc + (size_t)jj * 4096 + ct * 2048 + lane * 8;
    #pragma unroll
    for (int s = 0; s < 4; ++s)
      __builtin_amdgcn_global_load_lds(
          (const __attribute__((address_space(1))) void*)(gp + s * 512),
          (__attribute__((address_space(3))) void*)((uint8_t*)stage + wv * 12288 + ring * 4096 + s * 1024),
          16, 0, 0);
  };

  auto compute = [&](int jj, int ring, int vm) {
    if (vm == 8)      asm volatile("s_waitcnt vmcnt(8)" ::: "memory");
    else if (vm == 4) asm volatile("s_waitcnt vmcnt(4)" ::: "memory");
    else              asm volatile("s_waitcnt vmcnt(0)" ::: "memory");
    __builtin_amdgcn_sched_barrier(0);
    const uint32_t lb = stg + ring * 4096 + lane * 16;
    u32x4v Bf[4];
    asm volatile("ds_read_b128 %0, %1"             : "=v"(Bf[0]) : "v"(lb));
    asm volatile("ds_read_b128 %0, %1 offset:1024" : "=v"(Bf[1]) : "v"(lb));
    asm volatile("ds_read_b128 %0, %1 offset:2048" : "=v"(Bf[2]) : "v"(lb));
    asm volatile("ds_read_b128 %0, %1 offset:3072" : "=v"(Bf[3]) : "v"(lb));
    uint32_t xr[4];
    const uint32_t xo = (uint32_t)(jj * 2);
    asm volatile("ds_read_u16 %0, %1" : "=v"(xr[0]) : "v"(xad[0] + xo));
    asm volatile("ds_read_u16 %0, %1" : "=v"(xr[1]) : "v"(xad[1] + xo));
    asm volatile("ds_read_u16 %0, %1" : "=v"(xr[2]) : "v"(xad[2] + xo));
    asm volatile("ds_read_u16 %0, %1" : "=v"(xr[3]) : "v"(xad[3] + xo));
    asm volatile("s_waitcnt lgkmcnt(0)" ::: "memory");
    __builtin_amdgcn_sched_barrier(0);
    #pragma unroll
    for (int T = 0; T < 4; ++T) {
      float xf = __builtin_bit_cast(float, xr[T] << 16);
      f32x2v xx; xx[0] = xf; xx[1] = xf;
      #pragma unroll
      for (int s = 0; s < 4; ++s) {
        f32x2v m0, m1, m2, m3;
        asm("v_pk_mul_f32 %0, %1, %2" : "=v"(m0) : "v"(xx), "v"(kk[T][s][0]));
        asm("v_pk_mul_f32 %0, %1, %2" : "=v"(m1) : "v"(xx), "v"(kk[T][s][1]));
        asm("v_pk_mul_f32 %0, %1, %2" : "=v"(m2) : "v"(xx), "v"(kk[T][s][2]));
        asm("v_pk_mul_f32 %0, %1, %2" : "=v"(m3) : "v"(xx), "v"(kk[T][s][3]));
        uint32_t p0, p1, p2, p3;
        asm("v_cvt_pk_bf16_f32 %0, %1, %2" : "=v"(p0) : "v"(m0[0]), "v"(m0[1]));
        asm("v_cvt_pk_bf16_f32 %0, %1, %2" : "=v"(p1) : "v"(m1[0]), "v"(m1[1]));
        asm("v_cvt_pk_bf16_f32 %0, %1, %2" : "=v"(p2) : "v"(m2[0]), "v"(m2[1]));
        asm("v_cvt_pk_bf16_f32 %0, %1, %2" : "=v"(p3) : "v"(m3[0]), "v"(m3[1]));
        u32x4v av; av[0] = p0; av[1] = p1; av[2] = p2; av[3] = p3;
        acc[T] = mfma16(av, Bf[s], acc[T]);
      }
    }
  };

  auto run_pass = [&](const u16* __restrict__ Wsrc) {
    #pragma unroll
    for (int T = 0; T < 4; ++T)
      #pragma unroll
      for (int r = 0; r < 16; ++r) acc[T][r] = 0.0f;
    issue(Wsrc, jidx(0), 0);
    issue(Wsrc, jidx(1), 1);
    issue(Wsrc, jidx(2), 2);
    int ring = 0;
    for (int i = 0; i < jn; ++i) {
      const int rem = jn - 1 - i;
      const int vm = rem >= 2 ? 8 : (rem == 1 ? 4 : 0);
      compute(jidx(i), ring, vm);
      if (i + 3 < jn) issue(Wsrc, jidx(i + 3), ring);
      ring = (ring == 2) ? 0 : ring + 1;
    }
  };

  auto combine = [&]() {
    #pragma unroll
    for (int T = 0; T < 4; ++T)
      #pragma unroll
      for (int r = 0; r < 16; ++r) {
        const int rr = (r & 3) + 8 * (r >> 2) + 4 * half;
        atomicAdd(&vl[(T * 32 + rr) * 68 + ct * 32 + bl], acc[T][r]);
      }
  };

  // ---------------- pass 1: v[b,k] ----------------
  run_pass(w1f);
  combine();
  __syncthreads();

  // reload kk <- v (f32)
  #pragma unroll
  for (int T = 0; T < 4; ++T)
    #pragma unroll
    for (int s = 0; s < 4; ++s) {
      const float* vp = &vl[(T * 32 + bl) * 68 + s * 16 + half * 8];
      f32x4v a = *reinterpret_cast<const f32x4v*>(vp);
      f32x4v b = *reinterpret_cast<const f32x4v*>(vp + 4);
      kk[T][s][0][0] = a[0]; kk[T][s][0][1] = a[1];
      kk[T][s][1][0] = a[2]; kk[T][s][1][1] = a[3];
      kk[T][s][2][0] = b[0]; kk[T][s][2][1] = b[1];
      kk[T][s][3][0] = b[2]; kk[T][s][3][1] = b[3];
    }
  __syncthreads();
  for (int idx = t; idx < 128 * 68; idx += 512) vl[idx] = 0.0f;
  __syncthreads();

  // ---------------- pass 2: out[b,e] ----------------
  run_pass(w2f);
  combine();
  __syncthreads();

  for (int q = t; q < 2048; q += 512) {
    const int b = q >> 4, c = (q & 15) * 4;
    f32x4v v4 = *reinterpret_cast<const f32x4v*>(&vl[b * 68 + c]);
    f32x4v o;
    o[0] = v4[0] * 0.125f; o[1] = v4[1] * 0.125f;
    o[2] = v4[2] * 0.125f; o[3] = v4[3] * 0.125f;
    *reinterpret_cast<f32x4v*>(&out[(base + b) * 64 + c]) = o;
  }
}

extern "C" void kernel_launch(void* const* d_in, const int* in_sizes, int n_in,
                              void* d_out, int out_size, void* d_ws, size_t ws_size,
                              hipStream_t stream) {
  const float* x = (const float*)d_in[0];
  const float* g = (const float*)d_in[1];
  const float* W = (const float*)d_in[2];
  float* o = (float*)d_out;
  u16* w1f = (u16*)d_ws;
  u16* w2f = w1f + 65 * 4096;
  hipLaunchKernelGGL(prep_w, dim3(65), dim3(256), 0, stream, W, w1f, w2f);
  hipLaunchKernelGGL(rquad_main, dim3(256), dim3(512), 0, stream, x, g, w1f, w2f, o);
}

// Round 8
// 55.629 us; speedup vs baseline: 2.6228x; 2.6228x over previous
//
#include <hip/hip_runtime.h>
#include <stdint.h>

typedef __bf16    bf16x8  __attribute__((ext_vector_type(8)));
typedef float     f32x16v __attribute__((ext_vector_type(16)));
typedef float     f32x4v  __attribute__((ext_vector_type(4)));
typedef uint32_t  u32x4v  __attribute__((ext_vector_type(4)));
typedef unsigned short u16;

__device__ __forceinline__ u16 f32_to_bf16_rne(float f) {
  uint32_t u = __builtin_bit_cast(uint32_t, f);
  return (u16)((u + 0x7fffu + ((u >> 16) & 1u)) >> 16);
}

__device__ __forceinline__ uint32_t cvt_pk2(float a, float b) {
  uint32_t r;
  asm("v_cvt_pk_bf16_f32 %0, %1, %2" : "=v"(r) : "v"(a), "v"(b));
  return r;
}

__device__ __forceinline__ f32x16v mfma16(u32x4v a, u32x4v b, f32x16v c) {
  return __builtin_amdgcn_mfma_f32_32x32x16_bf16(
      __builtin_bit_cast(bf16x8, a), __builtin_bit_cast(bf16x8, b), c, 0, 0, 0);
}

// prep: W f32 [65][i=64][k=64] -> fragment-major bf16 arrays (B-operand form).
// elem idx = jj*4096 + (ct*4+s)*512 + l*8 + e  (l = lane)
//   w1f: W[jj][ i=s*16+(l>>5)*8+e ][ k=ct*32+(l&31) ]
//   w2f: W[jj][ e_row=ct*32+(l&31) ][ k=s*16+(l>>5)*8+e ]
__global__ __launch_bounds__(256) void prep_w(const float* __restrict__ W,
                                              u16* __restrict__ w1f,
                                              u16* __restrict__ w2f) {
  __shared__ float Wl[4096];
  const int jj = blockIdx.x;
  const int t  = threadIdx.x;
  for (int idx = t; idx < 4096; idx += 256) Wl[idx] = W[jj * 4096 + idx];
  __syncthreads();
  for (int p = t; p < 512; p += 256) {
    const int c2 = p >> 6, l = p & 63;
    const int ct = c2 >> 2, s = c2 & 3;
    const int rowA = ct * 32 + (l & 31);
    const int k0   = s * 16 + (l >> 5) * 8;
    u16 v1[8], v2[8];
    #pragma unroll
    for (int e = 0; e < 8; ++e) {
      v2[e] = f32_to_bf16_rne(Wl[rowA * 64 + k0 + e]);
      v1[e] = f32_to_bf16_rne(Wl[(k0 + e) * 64 + rowA]);
    }
    u32x4v pk1, pk2;
    #pragma unroll
    for (int q = 0; q < 4; ++q) {
      pk1[q] = (uint32_t)v1[2*q] | ((uint32_t)v1[2*q+1] << 16);
      pk2[q] = (uint32_t)v2[2*q] | ((uint32_t)v2[2*q+1] << 16);
    }
    *reinterpret_cast<u32x4v*>(w1f + jj * 4096 + p * 8) = pk1;
    *reinterpret_cast<u32x4v*>(w2f + jj * 4096 + p * 8) = pk2;
  }
}

// main: grid 256 (1 block/CU), 256 thr (4 waves), BB=128 samples (32/wave).
// W chunk-resident in LDS (2x64KB dbuf, 8 j/chunk, global_load_lds, one
// barrier/chunk). Inner loop: pure LDS + VALU + MFMA, no memory inline-asm,
// no global loads. Wave owns its 32 samples across ALL j -> no cross-wave
// combine; v transposed via per-wave LDS scratch between passes.
__global__ __launch_bounds__(256) void rquad_main(
    const float* __restrict__ x, const float* __restrict__ g,
    const u16* __restrict__ w1f, const u16* __restrict__ w2f,
    float* __restrict__ out) {
  __shared__ u16 stage[2][8 * 4096];   // 2 x 64 KB
  __shared__ u16 x1b[128 * 66];        // bf16 x1, 16.9 KB

  const int t    = threadIdx.x;
  const int lane = t & 63;
  const int wv   = t >> 6;          // 0..3
  const int bl   = lane & 31;
  const int half = lane >> 5;
  const long base = (long)blockIdx.x * 128;
  const int  srow = wv * 32 + bl;   // this lane's sample row (block-local)

  for (int idx = t; idx < 128 * 64; idx += 256) {
    int s = idx >> 6, c = idx & 63;
    x1b[s * 66 + c] = f32_to_bf16_rne(x[(base + s) * 64 + c]);
  }
  if (t < 128) x1b[t * 66 + 64] = (u16)0x3F80;  // bias 1.0

  // K-side slice (g for pass1, v for pass2): k = s*16 + half*8 + 0..7
  f32x4v ka[4], kb[4];
  #pragma unroll
  for (int s = 0; s < 4; ++s) {
    const float* gp = g + (base + srow) * 64 + s * 16 + half * 8;
    ka[s] = *reinterpret_cast<const f32x4v*>(gp);
    kb[s] = *reinterpret_cast<const f32x4v*>(gp + 4);
  }

  f32x16v acc0, acc1;

  auto stage_chunk = [&](const u16* __restrict__ Wsrc, int c, int buf) {
    const int j0 = c * 8;
    const int nj = (j0 + 8 <= 65) ? 8 : (65 - j0);
    const int nq = nj * 8;               // 1KB wave-loads
    for (int q = wv; q < nq; q += 4) {
      const u16* src = Wsrc + (size_t)j0 * 4096 + q * 512 + lane * 8;
      __builtin_amdgcn_global_load_lds(
          (const __attribute__((address_space(1))) void*)src,
          (__attribute__((address_space(3))) void*)(&stage[buf][q * 512]),
          16, 0, 0);
    }
  };

  auto compute_j = [&](int jl, int buf, int jglob) {
    const u16* sb = &stage[buf][jl * 4096];
    u32x4v B0[4], B1[4];
    #pragma unroll
    for (int s = 0; s < 4; ++s) {
      B0[s] = *reinterpret_cast<const u32x4v*>(sb + s * 512 + lane * 8);
      B1[s] = *reinterpret_cast<const u32x4v*>(sb + 2048 + s * 512 + lane * 8);
    }
    const u16 xu = x1b[srow * 66 + jglob];
    const float xf = __builtin_bit_cast(float, (uint32_t)xu << 16);
    u32x4v av[4];
    #pragma unroll
    for (int s = 0; s < 4; ++s) {
      av[s][0] = cvt_pk2(xf * ka[s][0], xf * ka[s][1]);
      av[s][1] = cvt_pk2(xf * ka[s][2], xf * ka[s][3]);
      av[s][2] = cvt_pk2(xf * kb[s][0], xf * kb[s][1]);
      av[s][3] = cvt_pk2(xf * kb[s][2], xf * kb[s][3]);
    }
    #pragma unroll
    for (int s = 0; s < 4; ++s) {
      acc0 = mfma16(av[s], B0[s], acc0);
      acc1 = mfma16(av[s], B1[s], acc1);
    }
  };

  auto run_pass = [&](const u16* __restrict__ Wsrc) {
    #pragma unroll
    for (int r = 0; r < 16; ++r) { acc0[r] = 0.0f; acc1[r] = 0.0f; }
    stage_chunk(Wsrc, 0, 0);
    __syncthreads();                       // chunk 0 landed
    for (int c = 0; c < 9; ++c) {
      if (c + 1 < 9) stage_chunk(Wsrc, c + 1, (c + 1) & 1);
      const int j0 = c * 8;
      if (j0 + 8 <= 65) {
        #pragma unroll
        for (int jl = 0; jl < 8; ++jl) compute_j(jl, c & 1, j0 + jl);
      } else {
        compute_j(0, c & 1, j0);           // last chunk: j=64 only
      }
      __syncthreads();                     // next chunk landed; all done reading cur
    }
  };

  __syncthreads();  // x1b ready

  // ---------------- pass 1: v[b,k] (complete per wave, in acc) ----------------
  run_pass(w1f);

  // transpose v via per-wave LDS scratch (stage is free after last barrier)
  {
    float* scr = reinterpret_cast<float*>(&stage[0][0]) + wv * (32 * 68);
    #pragma unroll
    for (int r = 0; r < 16; ++r) {
      const int rr = (r & 3) + 8 * (r >> 2) + 4 * half;   // sample row in tile
      scr[rr * 68 + bl]      = acc0[r];                   // k col = bl
      scr[rr * 68 + 32 + bl] = acc1[r];                   // k col = 32+bl
    }
    // wave-internal write->read; compiler orders via lgkmcnt
    #pragma unroll
    for (int s = 0; s < 4; ++s) {
      const float* vp = scr + bl * 68 + s * 16 + half * 8;
      ka[s] = *reinterpret_cast<const f32x4v*>(vp);
      kb[s] = *reinterpret_cast<const f32x4v*>(vp + 4);
    }
  }
  __syncthreads();  // all waves done with scratch before pass2 staging

  // ---------------- pass 2: out[b,e] ----------------
  run_pass(w2f);

  // epilogue: acc -> LDS bounce -> coalesced store (stage free again)
  {
    float* ocr = reinterpret_cast<float*>(&stage[0][0]) + wv * (32 * 68);
    #pragma unroll
    for (int r = 0; r < 16; ++r) {
      const int rr = (r & 3) + 8 * (r >> 2) + 4 * half;
      ocr[rr * 68 + bl]      = acc0[r] * 0.125f;
      ocr[rr * 68 + 32 + bl] = acc1[r] * 0.125f;
    }
  }
  __syncthreads();
  for (int idx = t; idx < 2048; idx += 256) {     // 2048 f32x4 quads
    const int b = idx >> 4, c4 = (idx & 15) * 4;
    const float* src = reinterpret_cast<const float*>(&stage[0][0]) +
                       (b >> 5) * (32 * 68) + (b & 31) * 68 + c4;
    f32x4v v4 = *reinterpret_cast<const f32x4v*>(src);
    *reinterpret_cast<f32x4v*>(out + (base + b) * 64 + c4) = v4;
  }
}

extern "C" void kernel_launch(void* const* d_in, const int* in_sizes, int n_in,
                              void* d_out, int out_size, void* d_ws, size_t ws_size,
                              hipStream_t stream) {
  const float* x = (const float*)d_in[0];
  const float* g = (const float*)d_in[1];
  const float* W = (const float*)d_in[2];
  float* o = (float*)d_out;
  u16* w1f = (u16*)d_ws;
  u16* w2f = w1f + 65 * 4096;
  hipLaunchKernelGGL(prep_w, dim3(65), dim3(256), 0, stream, W, w1f, w2f);
  hipLaunchKernelGGL(rquad_main, dim3(256), dim3(256), 0, stream, x, g, w1f, w2f, o);
}

// Round 9
// 52.971 us; speedup vs baseline: 2.7545x; 1.0502x over previous
//
#include <hip/hip_runtime.h>
#include <stdint.h>

typedef _Float16  f16;
typedef f16       f16x2  __attribute__((ext_vector_type(2)));
typedef f16       f16x8  __attribute__((ext_vector_type(8)));
typedef float     f32x16v __attribute__((ext_vector_type(16)));
typedef float     f32x4v  __attribute__((ext_vector_type(4)));
typedef uint32_t  u32x4v  __attribute__((ext_vector_type(4)));
typedef unsigned short u16;

__device__ __forceinline__ f32x16v mfma16h(u32x4v a, u32x4v b, f32x16v c) {
  return __builtin_amdgcn_mfma_f32_32x32x16_f16(
      __builtin_bit_cast(f16x8, a), __builtin_bit_cast(f16x8, b), c, 0, 0, 0);
}

// prep: W f32 [65][i=64][k=64] -> fragment-major f16 arrays (B-operand form).
// elem idx = jj*4096 + (ct*4+s)*512 + l*8 + e  (l = lane)
//   w1h: W[jj][ i=s*16+(l>>5)*8+e ][ k=ct*32+(l&31) ]
//   w2h: W[jj][ e_row=ct*32+(l&31) ][ k=s*16+(l>>5)*8+e ]
__global__ __launch_bounds__(256) void prep_w(const float* __restrict__ W,
                                              u16* __restrict__ w1h,
                                              u16* __restrict__ w2h) {
  __shared__ float Wl[4096];
  const int jj = blockIdx.x;
  const int t  = threadIdx.x;
  for (int idx = t; idx < 4096; idx += 256) Wl[idx] = W[jj * 4096 + idx];
  __syncthreads();
  for (int p = t; p < 512; p += 256) {
    const int c2 = p >> 6, l = p & 63;
    const int ct = c2 >> 2, s = c2 & 3;
    const int rowA = ct * 32 + (l & 31);
    const int k0   = s * 16 + (l >> 5) * 8;
    u16 v1[8], v2[8];
    #pragma unroll
    for (int e = 0; e < 8; ++e) {
      v2[e] = __builtin_bit_cast(u16, (f16)Wl[rowA * 64 + k0 + e]);
      v1[e] = __builtin_bit_cast(u16, (f16)Wl[(k0 + e) * 64 + rowA]);
    }
    u32x4v pk1, pk2;
    #pragma unroll
    for (int q = 0; q < 4; ++q) {
      pk1[q] = (uint32_t)v1[2*q] | ((uint32_t)v1[2*q+1] << 16);
      pk2[q] = (uint32_t)v2[2*q] | ((uint32_t)v2[2*q+1] << 16);
    }
    *reinterpret_cast<u32x4v*>(w1h + jj * 4096 + p * 8) = pk1;
    *reinterpret_cast<u32x4v*>(w2h + jj * 4096 + p * 8) = pk2;
  }
}

// main: grid 256 (1 block/CU), 512 thr (8 waves = jq2 x p2 x ct2), BB=128.
// Two j-stream chunk pipelines (A: j=0..32, B: j=33..64), 4 x 32KB LDS bufs.
// Wave owns 2 sample-tiles (T=2) and one ct (k/e half): B-reads/MFMA = 0.5.
// fp16 A-build: v_pk_mul_f16 only (no cvt). v combined across jq via LDS.
__global__ __launch_bounds__(512, 2) void rquad_main(
    const float* __restrict__ x, const float* __restrict__ g,
    const u16* __restrict__ w1h, const u16* __restrict__ w2h,
    float* __restrict__ out) {
  __shared__ u16 stage[4][4 * 4096];   // 4 bufs x 32 KB = 128 KB
  __shared__ u16 x1b[128 * 66];        // f16 x1, 16.9 KB

  const int t    = threadIdx.x;
  const int lane = t & 63;
  const int wv   = t >> 6;
  const int jq   = wv >> 2;         // j-stream
  const int p    = (wv >> 1) & 1;   // tile-pair
  const int ct   = wv & 1;          // k/e column half
  const int bl   = lane & 31;
  const int half = lane >> 5;
  const long base = (long)blockIdx.x * 128;
  const int r0 = p * 64 + bl;       // sample row, tile 2p
  const int r1 = r0 + 32;           // sample row, tile 2p+1

  for (int idx = t; idx < 128 * 64; idx += 512) {
    int s = idx >> 6, c = idx & 63;
    x1b[s * 66 + c] = __builtin_bit_cast(u16, (f16)x[(base + s) * 64 + c]);
  }
  if (t < 128) x1b[t * 66 + 64] = (u16)0x3C00;  // f16 1.0

  // per-lane K-slices (g pass1, v pass2) as f16 pairs: z[tile][s][pair]
  f16x2 z0[4][4], z1[4][4];
  #pragma unroll
  for (int s = 0; s < 4; ++s) {
    const float* gp0 = g + (base + r0) * 64 + s * 16 + half * 8;
    const float* gp1 = g + (base + r1) * 64 + s * 16 + half * 8;
    f32x4v a = *reinterpret_cast<const f32x4v*>(gp0);
    f32x4v b = *reinterpret_cast<const f32x4v*>(gp0 + 4);
    f32x4v c = *reinterpret_cast<const f32x4v*>(gp1);
    f32x4v d = *reinterpret_cast<const f32x4v*>(gp1 + 4);
    z0[s][0] = f16x2{(f16)a[0], (f16)a[1]}; z0[s][1] = f16x2{(f16)a[2], (f16)a[3]};
    z0[s][2] = f16x2{(f16)b[0], (f16)b[1]}; z0[s][3] = f16x2{(f16)b[2], (f16)b[3]};
    z1[s][0] = f16x2{(f16)c[0], (f16)c[1]}; z1[s][1] = f16x2{(f16)c[2], (f16)c[3]};
    z1[s][2] = f16x2{(f16)d[0], (f16)d[1]}; z1[s][3] = f16x2{(f16)d[2], (f16)d[3]};
  }

  f32x16v acc0, acc1;

  auto stage_chunk = [&](const u16* __restrict__ Wsrc, int stream, int ci) {
    if (ci > 8 || (stream == 1 && ci == 8)) return;
    if (jq != stream) return;
    const int j0 = (stream == 0) ? ci * 4 : 33 + ci * 4;
    const int nq = (stream == 0 && ci == 8) ? 8 : 32;     // 1-KB wave loads
    const int buf = stream * 2 + (ci & 1);
    const int w4 = wv & 3;
    for (int q = w4; q < nq; q += 4) {
      const u16* src = Wsrc + (size_t)(j0 + (q >> 3)) * 4096 + (q & 7) * 512 + lane * 8;
      __builtin_amdgcn_global_load_lds(
          (const __attribute__((address_space(1))) void*)src,
          (__attribute__((address_space(3))) void*)(&stage[buf][q * 512]),
          16, 0, 0);
    }
  };

  auto compute_j = [&](int buf, int jl, int jglob) {
    const u16* sb = &stage[buf][jl * 4096 + ct * 2048];
    u32x4v B[4];
    #pragma unroll
    for (int s = 0; s < 4; ++s)
      B[s] = *reinterpret_cast<const u32x4v*>(sb + s * 512 + lane * 8);
    const f16 xh0 = __builtin_bit_cast(f16, x1b[r0 * 66 + jglob]);
    const f16 xh1 = __builtin_bit_cast(f16, x1b[r1 * 66 + jglob]);
    const f16x2 xx0 = f16x2{xh0, xh0}, xx1 = f16x2{xh1, xh1};
    #pragma unroll
    for (int s = 0; s < 4; ++s) {
      u32x4v a0, a1;
      #pragma unroll
      for (int q = 0; q < 4; ++q) {
        f16x2 p0 = xx0 * z0[s][q];
        f16x2 p1 = xx1 * z1[s][q];
        a0[q] = __builtin_bit_cast(uint32_t, p0);
        a1[q] = __builtin_bit_cast(uint32_t, p1);
      }
      acc0 = mfma16h(a0, B[s], acc0);
      acc1 = mfma16h(a1, B[s], acc1);
    }
  };

  auto run_pass = [&](const u16* __restrict__ Wsrc) {
    #pragma unroll
    for (int r = 0; r < 16; ++r) { acc0[r] = 0.0f; acc1[r] = 0.0f; }
    stage_chunk(Wsrc, 0, 0);
    stage_chunk(Wsrc, 1, 0);
    __syncthreads();
    for (int st = 0; st <= 8; ++st) {
      stage_chunk(Wsrc, 0, st + 1);
      stage_chunk(Wsrc, 1, st + 1);
      if (jq == 0) {
        const int buf = st & 1;
        if (st < 8) {
          #pragma unroll
          for (int jl = 0; jl < 4; ++jl) compute_j(buf, jl, st * 4 + jl);
        } else {
          compute_j(buf, 0, 32);
        }
      } else {
        if (st < 8) {
          const int buf = 2 + (st & 1);
          #pragma unroll
          for (int jl = 0; jl < 4; ++jl) compute_j(buf, jl, 33 + st * 4 + jl);
        }
      }
      __syncthreads();
    }
  };

  __syncthreads();  // x1b ready

  // ---------------- pass 1: v[b,k] ----------------
  run_pass(w1h);

  float* vl = reinterpret_cast<float*>(&stage[0][0]);  // [128][68] overlay
  if (jq == 0) {
    #pragma unroll
    for (int r = 0; r < 16; ++r) {
      const int rr = (r & 3) + 8 * (r >> 2) + 4 * half;
      vl[(p * 64 + rr) * 68 + ct * 32 + bl]      = acc0[r];
      vl[(p * 64 + 32 + rr) * 68 + ct * 32 + bl] = acc1[r];
    }
  }
  __syncthreads();
  if (jq == 1) {
    #pragma unroll
    for (int r = 0; r < 16; ++r) {
      const int rr = (r & 3) + 8 * (r >> 2) + 4 * half;
      vl[(p * 64 + rr) * 68 + ct * 32 + bl]      += acc0[r];
      vl[(p * 64 + 32 + rr) * 68 + ct * 32 + bl] += acc1[r];
    }
  }
  __syncthreads();
  // z <- v (f32 -> f16)
  #pragma unroll
  for (int s = 0; s < 4; ++s) {
    const float* vp0 = &vl[r0 * 68 + s * 16 + half * 8];
    const float* vp1 = &vl[r1 * 68 + s * 16 + half * 8];
    f32x4v a = *reinterpret_cast<const f32x4v*>(vp0);
    f32x4v b = *reinterpret_cast<const f32x4v*>(vp0 + 4);
    f32x4v c = *reinterpret_cast<const f32x4v*>(vp1);
    f32x4v d = *reinterpret_cast<const f32x4v*>(vp1 + 4);
    z0[s][0] = f16x2{(f16)a[0], (f16)a[1]}; z0[s][1] = f16x2{(f16)a[2], (f16)a[3]};
    z0[s][2] = f16x2{(f16)b[0], (f16)b[1]}; z0[s][3] = f16x2{(f16)b[2], (f16)b[3]};
    z1[s][0] = f16x2{(f16)c[0], (f16)c[1]}; z1[s][1] = f16x2{(f16)c[2], (f16)c[3]};
    z1[s][2] = f16x2{(f16)d[0], (f16)d[1]}; z1[s][3] = f16x2{(f16)d[2], (f16)d[3]};
  }
  __syncthreads();  // scratch free before pass-2 staging

  // ---------------- pass 2: out[b,e] ----------------
  run_pass(w2h);

  if (jq == 0) {
    #pragma unroll
    for (int r = 0; r < 16; ++r) {
      const int rr = (r & 3) + 8 * (r >> 2) + 4 * half;
      vl[(p * 64 + rr) * 68 + ct * 32 + bl]      = acc0[r];
      vl[(p * 64 + 32 + rr) * 68 + ct * 32 + bl] = acc1[r];
    }
  }
  __syncthreads();
  if (jq == 1) {
    #pragma unroll
    for (int r = 0; r < 16; ++r) {
      const int rr = (r & 3) + 8 * (r >> 2) + 4 * half;
      vl[(p * 64 + rr) * 68 + ct * 32 + bl]      += acc0[r];
      vl[(p * 64 + 32 + rr) * 68 + ct * 32 + bl] += acc1[r];
    }
  }
  __syncthreads();
  for (int idx = t; idx < 2048; idx += 512) {
    const int b = idx >> 4, c4 = (idx & 15) * 4;
    f32x4v v4 = *reinterpret_cast<const f32x4v*>(&vl[b * 68 + c4]);
    f32x4v o;
    o[0] = v4[0] * 0.125f; o[1] = v4[1] * 0.125f;
    o[2] = v4[2] * 0.125f; o[3] = v4[3] * 0.125f;
    *reinterpret_cast<f32x4v*>(out + (base + b) * 64 + c4) = o;
  }
}

extern "C" void kernel_launch(void* const* d_in, const int* in_sizes, int n_in,
                              void* d_out, int out_size, void* d_ws, size_t ws_size,
                              hipStream_t stream) {
  const float* x = (const float*)d_in[0];
  const float* g = (const float*)d_in[1];
  const float* W = (const float*)d_in[2];
  float* o = (float*)d_out;
  u16* w1h = (u16*)d_ws;                    // 65*4096 f16 = 520 KiB
  u16* w2h = w1h + 65 * 4096;               // another 520 KiB
  hipLaunchKernelGGL(prep_w, dim3(65), dim3(256), 0, stream, W, w1h, w2h);
  hipLaunchKernelGGL(rquad_main, dim3(256), dim3(512), 0, stream, x, g, w1h, w2h, o);
}

// Round 10
// 52.307 us; speedup vs baseline: 2.7895x; 1.0127x over previous
//
#include <hip/hip_runtime.h>
#include <stdint.h>

typedef _Float16  f16;
typedef f16       f16x2  __attribute__((ext_vector_type(2)));
typedef f16       f16x8  __attribute__((ext_vector_type(8)));
typedef float     f32x16v __attribute__((ext_vector_type(16)));
typedef float     f32x4v  __attribute__((ext_vector_type(4)));
typedef uint32_t  u32x4v  __attribute__((ext_vector_type(4)));
typedef unsigned short u16;

__device__ __forceinline__ f32x16v mfma16h(u32x4v a, u32x4v b, f32x16v c) {
  return __builtin_amdgcn_mfma_f32_32x32x16_f16(
      __builtin_bit_cast(f16x8, a), __builtin_bit_cast(f16x8, b), c, 0, 0, 0);
}

// prep: W f32 [65][i=64][k=64] -> fragment-major f16 arrays (B-operand form).
// elem idx = jj*4096 + (ct*4+s)*512 + l*8 + e  (l = lane)
//   w1h: W[jj][ i=s*16+(l>>5)*8+e ][ k=ct*32+(l&31) ]
//   w2h: W[jj][ e_row=ct*32+(l&31) ][ k=s*16+(l>>5)*8+e ]
__global__ __launch_bounds__(256) void prep_w(const float* __restrict__ W,
                                              u16* __restrict__ w1h,
                                              u16* __restrict__ w2h) {
  __shared__ float Wl[4096];
  const int jj = blockIdx.x;
  const int t  = threadIdx.x;
  for (int idx = t; idx < 4096; idx += 256) Wl[idx] = W[jj * 4096 + idx];
  __syncthreads();
  for (int pq = t; pq < 512; pq += 256) {
    const int c2 = pq >> 6, l = pq & 63;
    const int ct = c2 >> 2, s = c2 & 3;
    const int rowA = ct * 32 + (l & 31);
    const int k0   = s * 16 + (l >> 5) * 8;
    u16 v1[8], v2[8];
    #pragma unroll
    for (int e = 0; e < 8; ++e) {
      v2[e] = __builtin_bit_cast(u16, (f16)Wl[rowA * 64 + k0 + e]);
      v1[e] = __builtin_bit_cast(u16, (f16)Wl[(k0 + e) * 64 + rowA]);
    }
    u32x4v pk1, pk2;
    #pragma unroll
    for (int q = 0; q < 4; ++q) {
      pk1[q] = (uint32_t)v1[2*q] | ((uint32_t)v1[2*q+1] << 16);
      pk2[q] = (uint32_t)v2[2*q] | ((uint32_t)v2[2*q+1] << 16);
    }
    *reinterpret_cast<u32x4v*>(w1h + jj * 4096 + pq * 8) = pk1;
    *reinterpret_cast<u32x4v*>(w2h + jj * 4096 + pq * 8) = pk2;
  }
}

// main: grid 256 (1 block/CU), 512 thr (8 waves = jq2 x p2 x ct2), BB=128.
// B s-chunks 0,1 staged in LDS (read-once), s-chunks 2,3 loaded straight
// from L2 to VGPRs. x1 packed f16-pairs, 1 ds_read_b32 per compute_j.
__global__ __launch_bounds__(512, 2) void rquad_main(
    const float* __restrict__ x, const float* __restrict__ g,
    const u16* __restrict__ w1h, const u16* __restrict__ w2h,
    float* __restrict__ out) {
  __shared__ u16      stage[4][8192];   // 4 bufs x 16 KB (4j x [ct2][s2][1KB])
  __shared__ float    vl[128 * 68];     // 34.8 KB combine / repack buffer
  __shared__ uint32_t x1p[65 * 64];     // 16.6 KB packed x1 f16-pairs

  const int t    = threadIdx.x;
  const int lane = t & 63;
  const int wv   = t >> 6;
  const int jq   = wv >> 2;         // j-stream: 0 -> j 0..32, 1 -> j 33..64
  const int p    = (wv >> 1) & 1;   // sample half
  const int ct   = wv & 1;          // output-column half
  const int bl   = lane & 31;
  const int half = lane >> 5;
  const long base = (long)blockIdx.x * 128;
  const int r0 = p * 64 + bl, r1 = r0 + 32;

  // prologue: coalesced x -> vl, then repack to x1p (pairs (r, r+32) per p)
  for (int q = t; q < 2048; q += 512) {
    const int row = q >> 4, c4 = (q & 15) * 4;
    *reinterpret_cast<f32x4v*>(&vl[row * 68 + c4]) =
        *reinterpret_cast<const f32x4v*>(&x[(base + row) * 64 + c4]);
  }
  __syncthreads();
  for (int idx = t; idx < 65 * 64; idx += 512) {
    const int j = idx >> 6, q = idx & 63, pp = q >> 5, qq = q & 31;
    uint32_t val;
    if (j == 64) val = 0x3C003C00u;                  // bias row = 1.0,1.0
    else {
      f16 a = (f16)vl[(pp * 64 + qq) * 68 + j];
      f16 b = (f16)vl[(pp * 64 + 32 + qq) * 68 + j];
      val = (uint32_t)__builtin_bit_cast(u16, a) |
            ((uint32_t)__builtin_bit_cast(u16, b) << 16);
    }
    x1p[idx] = val;
  }

  // z init from g (pass-1 K-side)
  f16x2 z0[4][4], z1[4][4];
  #pragma unroll
  for (int s = 0; s < 4; ++s) {
    const float* gp0 = g + (base + r0) * 64 + s * 16 + half * 8;
    const float* gp1 = g + (base + r1) * 64 + s * 16 + half * 8;
    f32x4v a = *reinterpret_cast<const f32x4v*>(gp0);
    f32x4v b = *reinterpret_cast<const f32x4v*>(gp0 + 4);
    f32x4v c = *reinterpret_cast<const f32x4v*>(gp1);
    f32x4v d = *reinterpret_cast<const f32x4v*>(gp1 + 4);
    z0[s][0] = f16x2{(f16)a[0],(f16)a[1]}; z0[s][1] = f16x2{(f16)a[2],(f16)a[3]};
    z0[s][2] = f16x2{(f16)b[0],(f16)b[1]}; z0[s][3] = f16x2{(f16)b[2],(f16)b[3]};
    z1[s][0] = f16x2{(f16)c[0],(f16)c[1]}; z1[s][1] = f16x2{(f16)c[2],(f16)c[3]};
    z1[s][2] = f16x2{(f16)d[0],(f16)d[1]}; z1[s][3] = f16x2{(f16)d[2],(f16)d[3]};
  }

  f32x16v acc0, acc1;

  auto stage_chunk = [&](const u16* __restrict__ Wsrc, int ci) {
    const int nch = (jq == 0) ? 9 : 8;
    if (ci >= nch) return;
    const int j0  = (jq == 0) ? ci * 4 : 33 + ci * 4;
    const int njs = (jq == 0 && ci == 8) ? 1 : 4;
    const int buf = jq * 2 + (ci & 1);
    #pragma unroll
    for (int u = 0; u < 2; ++u) {
      const int jl = 2 * p + u;
      if (jl < njs) {
        #pragma unroll
        for (int s = 0; s < 2; ++s) {
          const u16* src = Wsrc + (size_t)(j0 + jl) * 4096 + ct * 2048 + s * 512 + lane * 8;
          __builtin_amdgcn_global_load_lds(
              (const __attribute__((address_space(1))) void*)src,
              (__attribute__((address_space(3))) void*)(
                  &stage[buf][jl * 2048 + ct * 1024 + s * 512 + lane * 8]),
              16, 0, 0);
        }
      }
    }
  };

  auto compute_j = [&](const u16* __restrict__ Wsrc, int buf, int jl, int jglob) {
    // s=2,3 straight from L2 to regs (issued first, used last)
    const u16* gp = Wsrc + (size_t)jglob * 4096 + ct * 2048 + 1024 + lane * 8;
    u32x4v B2 = *reinterpret_cast<const u32x4v*>(gp);
    u32x4v B3 = *reinterpret_cast<const u32x4v*>(gp + 512);
    // s=0,1 from LDS (staged previous step)
    const u16* sb = &stage[buf][jl * 2048 + ct * 1024 + lane * 8];
    u32x4v B0 = *reinterpret_cast<const u32x4v*>(sb);
    u32x4v B1 = *reinterpret_cast<const u32x4v*>(sb + 512);
    const uint32_t xw = x1p[jglob * 64 + p * 32 + bl];
    const f16 xlo = __builtin_bit_cast(f16, (u16)(xw & 0xffffu));
    const f16 xhi = __builtin_bit_cast(f16, (u16)(xw >> 16));
    const f16x2 xx0 = f16x2{xlo, xlo}, xx1 = f16x2{xhi, xhi};
    u32x4v Bs[4] = {B0, B1, B2, B3};
    #pragma unroll
    for (int s = 0; s < 4; ++s) {
      u32x4v a0, a1;
      #pragma unroll
      for (int q = 0; q < 4; ++q) {
        a0[q] = __builtin_bit_cast(uint32_t, f16x2(xx0 * z0[s][q]));
        a1[q] = __builtin_bit_cast(uint32_t, f16x2(xx1 * z1[s][q]));
      }
      acc0 = mfma16h(a0, Bs[s], acc0);
      acc1 = mfma16h(a1, Bs[s], acc1);
    }
  };

  auto run_pass = [&](const u16* __restrict__ Wsrc) {
    #pragma unroll
    for (int r = 0; r < 16; ++r) { acc0[r] = 0.0f; acc1[r] = 0.0f; }
    stage_chunk(Wsrc, 0);
    __syncthreads();
    for (int st = 0; st < 9; ++st) {
      stage_chunk(Wsrc, st + 1);
      const int buf = jq * 2 + (st & 1);
      if (st < 8) {
        const int jbase = (jq == 0) ? st * 4 : 33 + st * 4;
        #pragma unroll
        for (int jl = 0; jl < 4; ++jl) compute_j(Wsrc, buf, jl, jbase + jl);
      } else if (jq == 0) {
        compute_j(Wsrc, buf, 0, 32);
      }
      __syncthreads();
    }
  };

  // ---------------- pass 1: v[b,k] ----------------
  run_pass(w1h);

  if (jq == 0) {
    #pragma unroll
    for (int r = 0; r < 16; ++r) {
      const int rr = (r & 3) + 8 * (r >> 2) + 4 * half;
      vl[(p * 64 + rr) * 68 + ct * 32 + bl]      = acc0[r];
      vl[(p * 64 + 32 + rr) * 68 + ct * 32 + bl] = acc1[r];
    }
  }
  __syncthreads();
  if (jq == 1) {
    #pragma unroll
    for (int r = 0; r < 16; ++r) {
      const int rr = (r & 3) + 8 * (r >> 2) + 4 * half;
      vl[(p * 64 + rr) * 68 + ct * 32 + bl]      += acc0[r];
      vl[(p * 64 + 32 + rr) * 68 + ct * 32 + bl] += acc1[r];
    }
  }
  __syncthreads();
  // z <- v (f32 -> f16)
  #pragma unroll
  for (int s = 0; s < 4; ++s) {
    const float* vp0 = &vl[r0 * 68 + s * 16 + half * 8];
    const float* vp1 = &vl[r1 * 68 + s * 16 + half * 8];
    f32x4v a = *reinterpret_cast<const f32x4v*>(vp0);
    f32x4v b = *reinterpret_cast<const f32x4v*>(vp0 + 4);
    f32x4v c = *reinterpret_cast<const f32x4v*>(vp1);
    f32x4v d = *reinterpret_cast<const f32x4v*>(vp1 + 4);
    z0[s][0] = f16x2{(f16)a[0],(f16)a[1]}; z0[s][1] = f16x2{(f16)a[2],(f16)a[3]};
    z0[s][2] = f16x2{(f16)b[0],(f16)b[1]}; z0[s][3] = f16x2{(f16)b[2],(f16)b[3]};
    z1[s][0] = f16x2{(f16)c[0],(f16)c[1]}; z1[s][1] = f16x2{(f16)c[2],(f16)c[3]};
    z1[s][2] = f16x2{(f16)d[0],(f16)d[1]}; z1[s][3] = f16x2{(f16)d[2],(f16)d[3]};
  }
  // no barrier needed: pass-2's first barrier orders vl-reads vs later writes

  // ---------------- pass 2: out[b,e] ----------------
  run_pass(w2h);

  if (jq == 0) {
    #pragma unroll
    for (int r = 0; r < 16; ++r) {
      const int rr = (r & 3) + 8 * (r >> 2) + 4 * half;
      vl[(p * 64 + rr) * 68 + ct * 32 + bl]      = acc0[r];
      vl[(p * 64 + 32 + rr) * 68 + ct * 32 + bl] = acc1[r];
    }
  }
  __syncthreads();
  if (jq == 1) {
    #pragma unroll
    for (int r = 0; r < 16; ++r) {
      const int rr = (r & 3) + 8 * (r >> 2) + 4 * half;
      vl[(p * 64 + rr) * 68 + ct * 32 + bl]      += acc0[r];
      vl[(p * 64 + 32 + rr) * 68 + ct * 32 + bl] += acc1[r];
    }
  }
  __syncthreads();
  for (int q = t; q < 2048; q += 512) {
    const int row = q >> 4, c4 = (q & 15) * 4;
    f32x4v v4 = *reinterpret_cast<const f32x4v*>(&vl[row * 68 + c4]);
    f32x4v o;
    o[0] = v4[0] * 0.125f; o[1] = v4[1] * 0.125f;
    o[2] = v4[2] * 0.125f; o[3] = v4[3] * 0.125f;
    *reinterpret_cast<f32x4v*>(&out[(base + row) * 64 + c4]) = o;
  }
}

extern "C" void kernel_launch(void* const* d_in, const int* in_sizes, int n_in,
                              void* d_out, int out_size, void* d_ws, size_t ws_size,
                              hipStream_t stream) {
  const float* x = (const float*)d_in[0];
  const float* g = (const float*)d_in[1];
  const float* W = (const float*)d_in[2];
  float* o = (float*)d_out;
  u16* w1h = (u16*)d_ws;                    // 65*4096 f16 = 520 KiB
  u16* w2h = w1h + 65 * 4096;               // another 520 KiB
  hipLaunchKernelGGL(prep_w, dim3(65), dim3(256), 0, stream, W, w1h, w2h);
  hipLaunchKernelGGL(rquad_main, dim3(256), dim3(512), 0, stream, x, g, w1h, w2h, o);
}